// Round 8
// baseline (1374.653 us; speedup 1.0000x reference)
//
#include <hip/hip_runtime.h>
#include <math.h>

#define NN 8192
#define EE 262144
#define KNN 25
#define INIT_COLS 1024
#define CAP 768
#define INF INFINITY

typedef unsigned int u32;
typedef unsigned long long u64;

__device__ __forceinline__ float lrelu02(float x){ return x > 0.f ? x : 0.2f*x; }
__device__ __forceinline__ u32 fkey(float f){ u32 b = __float_as_uint(f); return b ^ (u32)(((int)b >> 31) | (int)0x80000000); }

// ---------------- CSR build (by dst) ----------------
__global__ __launch_bounds__(256) void k_count(const int* __restrict__ dst, int* __restrict__ deg) {
  int e = blockIdx.x*256 + threadIdx.x;
  if (e < EE) atomicAdd(&deg[dst[e]], 1);
}

__global__ __launch_bounds__(1024) void k_scan(const int* __restrict__ deg, int* __restrict__ rowptr) {
  __shared__ int lds[1024];
  int t = threadIdx.x;
  int v[8]; int s = 0;
#pragma unroll
  for (int i=0;i<8;i++){ v[i] = deg[t*8+i]; s += v[i]; }
  lds[t] = s; __syncthreads();
  for (int off=1; off<1024; off<<=1) {
    int x = (t>=off)? lds[t-off] : 0;
    __syncthreads();
    lds[t] += x;
    __syncthreads();
  }
  int base = (t==0)? 0 : lds[t-1];
  if (t==0) rowptr[0] = 0;
  int run = base;
#pragma unroll
  for (int i=0;i<8;i++){ run += v[i]; rowptr[t*8+i+1] = run; }
}

__global__ __launch_bounds__(256) void k_scatter(const int* __restrict__ src, const int* __restrict__ dst,
                          const int* __restrict__ rowptr, int* __restrict__ cursor,
                          int* __restrict__ csr) {
  int e = blockIdx.x*256 + threadIdx.x;
  if (e < EE) {
    int d = dst[e];
    int p = rowptr[d] + atomicAdd(&cursor[d], 1);
    csr[p] = src[e];
  }
}

// ---------------- small GEMM: C[8192 x Ncols] = A[8192 x K] @ B[K x Ncols] ----------------
__global__ __launch_bounds__(256) void k_gemm_small(const float* __restrict__ A, const float* __restrict__ B,
                                                    float* __restrict__ C, int Ncols, int Kdim) {
  __shared__ float Al[50][65];
  __shared__ float Bl[50][65];
  int t = threadIdx.x;
  int tr = t >> 4, tc = t & 15;
  int r0 = blockIdx.x * 64, c0 = blockIdx.y * 64;
  float acc[4][4] = {};
  for (int kc = 0; kc < Kdim; kc += 50) {
    for (int fl = t; fl < 64*50; fl += 256) {
      int m = fl / 50, k = fl - m*50;
      Al[k][m] = A[(long)(r0+m)*Kdim + kc + k];
    }
    for (int fl = t; fl < 50*64; fl += 256) {
      int k = fl >> 6, c = fl & 63;
      int cg = c0 + c;
      Bl[k][c] = (cg < Ncols) ? B[(long)(kc+k)*Ncols + cg] : 0.f;
    }
    __syncthreads();
    for (int k = 0; k < 50; k++) {
      float a_[4], b_[4];
#pragma unroll
      for (int i=0;i<4;i++) a_[i] = Al[k][tr*4+i];
#pragma unroll
      for (int j=0;j<4;j++) b_[j] = Bl[k][tc*4+j];
#pragma unroll
      for (int i=0;i<4;i++)
#pragma unroll
        for (int j=0;j<4;j++) acc[i][j] += a_[i]*b_[j];
    }
    __syncthreads();
  }
#pragma unroll
  for (int i=0;i<4;i++){
    int r = r0 + tr*4 + i;
#pragma unroll
    for (int j=0;j<4;j++){
      int c = c0 + tc*4 + j;
      if (c < Ncols) C[(long)r*Ncols + c] = acc[i][j];
    }
  }
}

// ---------------- GAT attention coefficients ----------------
__global__ __launch_bounds__(256) void k_gat_coef(const float* __restrict__ xp, const float* __restrict__ as_w,
                                                  const float* __restrict__ ad_w, float* __restrict__ asb,
                                                  float* __restrict__ adb) {
  int g = blockIdx.x*256 + threadIdx.x;
  int n = g >> 2, q = g & 3;
  int h = q >> 1, sd = q & 1;
  const float4* xr = (const float4*)(xp + (long)n*200 + h*100);
  const float4* wr = (const float4*)((sd ? ad_w : as_w) + h*100);
  float acc = 0.f;
#pragma unroll
  for (int q4=0;q4<25;q4++){
    float4 xv = xr[q4], wv = wr[q4];
    acc += xv.x*wv.x + xv.y*wv.y + xv.z*wv.z + xv.w*wv.w;
  }
  (sd ? adb : asb)[n*2 + h] = acc;
}

// ---------------- GAT aggregation per dst node ----------------
__global__ __launch_bounds__(256) void k_gat_agg(const float* __restrict__ xp, const float* __restrict__ asb,
                                                 const float* __restrict__ adb, const int* __restrict__ rowptr,
                                                 const int* __restrict__ csr, const float* __restrict__ bias,
                                                 const float* __restrict__ bng, const float* __restrict__ bnb,
                                                 int bnrelu, float* __restrict__ out) {
  __shared__ int esrc[256];
  __shared__ float ew0[256], ew1[256];
  __shared__ float red[2][4];
  __shared__ float ohead[200];
  int i = blockIdx.x, t = threadIdx.x;
  int lane = t & 63, wv = t >> 6;
  int beg = rowptr[i];
  int deg = rowptr[i+1] - beg;
  float ad0 = adb[i*2+0], ad1 = adb[i*2+1];
  float m0 = -INF, m1 = -INF, z0 = 0.f, z1 = 0.f, acc = 0.f;
  int h = (t >= 100) ? 1 : 0;
  int tot = deg + 1;
  for (int base = 0; base < tot; base += 256) {
    int cnt = min(256, tot - base);
    int j = base + t;
    float e0 = -INF, e1 = -INF; int s = i;
    if (t < cnt) {
      if (j < deg) s = csr[beg + j];
      float as0 = asb[s*2+0], as1 = asb[s*2+1];
      e0 = lrelu02(as0 + ad0);
      e1 = lrelu02(as1 + ad1);
    }
    esrc[t] = s;
    float r0v = e0, r1v = e1;
    for (int off=32; off; off>>=1){ r0v = fmaxf(r0v, __shfl_xor(r0v,off)); r1v = fmaxf(r1v, __shfl_xor(r1v,off)); }
    if (lane == 0){ red[0][wv] = r0v; red[1][wv] = r1v; }
    __syncthreads();
    float nm0 = fmaxf(m0, fmaxf(fmaxf(red[0][0],red[0][1]), fmaxf(red[0][2],red[0][3])));
    float nm1 = fmaxf(m1, fmaxf(fmaxf(red[1][0],red[1][1]), fmaxf(red[1][2],red[1][3])));
    float w0 = (t<cnt)? expf(e0-nm0) : 0.f;
    float w1e = (t<cnt)? expf(e1-nm1) : 0.f;
    ew0[t] = w0; ew1[t] = w1e;
    float s0 = w0, s1 = w1e;
    for (int off=32; off; off>>=1){ s0 += __shfl_xor(s0,off); s1 += __shfl_xor(s1,off); }
    __syncthreads();
    if (lane == 0){ red[0][wv] = s0; red[1][wv] = s1; }
    __syncthreads();
    float cs0 = red[0][0]+red[0][1]+red[0][2]+red[0][3];
    float cs1 = red[1][0]+red[1][1]+red[1][2]+red[1][3];
    float rf0 = expf(m0 - nm0);
    float rf1 = expf(m1 - nm1);
    z0 = z0*rf0 + cs0; z1 = z1*rf1 + cs1;
    m0 = nm0; m1 = nm1;
    if (t < 200) {
      acc *= (h==0) ? rf0 : rf1;
      const float* ew = (h==0) ? ew0 : ew1;
      for (int jj = 0; jj < cnt; jj++) {
        acc += ew[jj] * xp[(long)esrc[jj]*200 + t];
      }
    }
    __syncthreads();
  }
  if (t < 200) ohead[t] = acc / ((h==0) ? z0 : z1);
  __syncthreads();
  if (t < 100) {
    float v = 0.5f*(ohead[t] + ohead[100+t]) + bias[t];
    if (bnrelu) {
      v = v * (bng[t]*rsqrtf(1.f+1e-5f)) + bnb[t];
      v = fmaxf(v, 0.f);
    }
    out[(long)i*100 + t] = v;
  }
}

// ---------------- row L2-normalize -> TRANSPOSED output xnT[100][8192] ----------------
__global__ __launch_bounds__(256) void k_norm(const float* __restrict__ x, float* __restrict__ xnT) {
  int w = threadIdx.x >> 6, lane = threadIdx.x & 63;
  long n = blockIdx.x*4 + w;
  float a = x[n*100 + lane];
  float b = (lane < 36) ? x[n*100 + 64 + lane] : 0.f;
  float ss = a*a + b*b;
  for (int off=32; off; off>>=1) ss += __shfl_xor(ss, off);
  float sc = 1.f / fmaxf(sqrtf(ss), 1e-12f);
  xnT[(long)lane*NN + n] = a*sc;
  if (lane < 36) xnT[(long)(64+lane)*NN + n] = b*sc;
}

// ---------------- sim init GEMM from xnT (materialized, cols [0, INIT_COLS)) ----------------
// K-chunk 25 (26.4 KB LDS -> 6 blocks/CU); fragment map rows {4tr+i, 64+4tr+i},
// cols {4tc+j, 64+4tc+j} -> b128 LDS reads are 2-way (free) / broadcast.
__global__ __launch_bounds__(256) void k_sim(const float* __restrict__ xnT, float* __restrict__ simbuf) {
  __shared__ float Al[25][132];
  __shared__ float Bl[25][132];
  int t = threadIdx.x;
  int tr = t >> 4, tc = t & 15;
  int r0 = blockIdx.x * 128;
  int cb = blockIdx.y * 128;
  float acc[8][8] = {};
  for (int kc = 0; kc < 100; kc += 25) {
    for (int fl = t; fl < 25*128; fl += 256) {
      int k = fl >> 7, m = fl & 127;
      const float* src = xnT + (long)(kc+k)*NN;
      Al[k][m] = src[r0 + m];
      Bl[k][m] = src[cb + m];
    }
    __syncthreads();
    for (int k = 0; k < 25; k++) {
      float4 a0 = *(const float4*)&Al[k][4*tr];
      float4 a1 = *(const float4*)&Al[k][4*tr + 64];
      float4 b0 = *(const float4*)&Bl[k][4*tc];
      float4 b1 = *(const float4*)&Bl[k][4*tc + 64];
      float a_[8] = {a0.x,a0.y,a0.z,a0.w,a1.x,a1.y,a1.z,a1.w};
      float b_[8] = {b0.x,b0.y,b0.z,b0.w,b1.x,b1.y,b1.z,b1.w};
#pragma unroll
      for (int i=0;i<8;i++)
#pragma unroll
        for (int j=0;j<8;j++) acc[i][j] += a_[i]*b_[j];
    }
    __syncthreads();
  }
#pragma unroll
  for (int i=0;i<8;i++){
    long r = r0 + ((i<4) ? (4*tr + i) : (64 + 4*tr + i - 4));
    float* crow = simbuf + r*(long)INIT_COLS + cb;
    float4 o0 = make_float4(acc[i][0],acc[i][1],acc[i][2],acc[i][3]);
    float4 o1 = make_float4(acc[i][4],acc[i][5],acc[i][6],acc[i][7]);
    *(float4*)&crow[4*tc]      = o0;
    *(float4*)&crow[64 + 4*tc] = o1;
  }
}

// ---------------- fused sim + threshold filter (cols [INIT_COLS, NN)) ----------------
// Same fragment map as k_sim; survivor compaction via 16-lane scan, one atomic
// per (row, block).
__global__ __launch_bounds__(256) void k_sim_f(const float* __restrict__ xnT, const u32* __restrict__ thr,
                                               int* __restrict__ cnt, u64* __restrict__ candbuf, int cbase) {
  __shared__ float Al[25][132];
  __shared__ float Bl[25][132];
  int t = threadIdx.x;
  int tr = t >> 4, tc = t & 15;
  int r0 = blockIdx.x * 128;
  int cb = blockIdx.y * 128;
  float acc[8][8] = {};
  for (int kc = 0; kc < 100; kc += 25) {
    for (int fl = t; fl < 25*128; fl += 256) {
      int k = fl >> 7, m = fl & 127;
      const float* src = xnT + (long)(kc+k)*NN;
      Al[k][m] = src[r0 + m];
      Bl[k][m] = src[cbase + cb + m];
    }
    __syncthreads();
    for (int k = 0; k < 25; k++) {
      float4 a0 = *(const float4*)&Al[k][4*tr];
      float4 a1 = *(const float4*)&Al[k][4*tr + 64];
      float4 b0 = *(const float4*)&Bl[k][4*tc];
      float4 b1 = *(const float4*)&Bl[k][4*tc + 64];
      float a_[8] = {a0.x,a0.y,a0.z,a0.w,a1.x,a1.y,a1.z,a1.w};
      float b_[8] = {b0.x,b0.y,b0.z,b0.w,b1.x,b1.y,b1.z,b1.w};
#pragma unroll
      for (int i=0;i<8;i++)
#pragma unroll
        for (int j=0;j<8;j++) acc[i][j] += a_[i]*b_[j];
    }
    __syncthreads();
  }
  int sub = t & 15;   // == tc; 16-lane groups share the same 8 rows (same tr)
#pragma unroll
  for (int i=0;i<8;i++){
    int r = r0 + ((i<4) ? (4*tr + i) : (64 + 4*tr + i - 4));
    u32 T = thr[r];
    unsigned m8 = 0;
#pragma unroll
    for (int j=0;j<8;j++) if (fkey(acc[i][j]) > T) m8 |= 1u<<j;
    int c_lane = __popc(m8);
    int pre = c_lane;
#pragma unroll
    for (int off=1; off<16; off<<=1){ int o = __shfl_up(pre, off, 16); if (sub >= off) pre += o; }
    int tot = __shfl(pre, 15, 16);
    if (tot > 0){
      int base = 0;
      if (sub == 15) base = atomicAdd(&cnt[r], tot);
      base = __shfl(base, 15, 16);
      int p = base + pre - c_lane;
#pragma unroll
      for (int j=0;j<8;j++) if (m8 & (1u<<j)){
        if (p < CAP){
          int c = cbase + cb + ((j<4) ? (4*tc + j) : (64 + 4*tc + j - 4));
          candbuf[(long)r*CAP + p] = ((u64)fkey(acc[i][j]) << 32) | (u32)(0xFFFFFFFFu - (u32)c);
        }
        p++;
      }
    }
  }
}

// ---------------- init top-k via exact radix select over INIT_COLS ----------------
__global__ __launch_bounds__(256) void k_topk_sel(const float* __restrict__ simbuf,
                                                  u64* __restrict__ candu, u32* __restrict__ thr) {
  __shared__ int hist[256];
  __shared__ int scr2[2];
  __shared__ int cgt, ceq;
  __shared__ u64 win[32];
  __shared__ u32 tie[INIT_COLS];
  int row = blockIdx.x, t = threadIdx.x, lane = t & 63, w = t >> 6;
  const float* srow = simbuf + (long)row*INIT_COLS;
  u32 kk[4]; int col[4];
  {
    int c0 = 4*t;
    float4 f = *(const float4*)&srow[c0];
    kk[0] = fkey(f.x); col[0] = c0;
    kk[1] = fkey(f.y); col[1] = c0+1;
    kk[2] = fkey(f.z); col[2] = c0+2;
    kk[3] = fkey(f.w); col[3] = c0+3;
  }
  u32 prefix = 0; int base_gt = 0;
#pragma unroll
  for (int lvl = 0; lvl < 4; lvl++) {
    int shift = 24 - 8*lvl;
    hist[t] = 0;
    if (lvl == 0 && t == 0) { cgt = 0; ceq = 0; }
    __syncthreads();
    u32 mhi = (lvl == 0) ? 0u : (0xFFFFFFFFu << (32 - 8*lvl));
#pragma unroll
    for (int i = 0; i < 4; i++)
      if ((kk[i] & mhi) == (prefix & mhi)) atomicAdd(&hist[(kk[i] >> shift) & 0xFF], 1);
    __syncthreads();
    if (w == 0) {
      int h0 = hist[4*lane], h1 = hist[4*lane+1], h2 = hist[4*lane+2], h3 = hist[4*lane+3];
      int s = h0 + h1 + h2 + h3;
      int acc = s;
      for (int off = 1; off < 64; off <<= 1) {
        int o = __shfl_down(acc, off);
        if (lane + off < 64) acc += o;
      }
      int T = base_gt + (acc - s);
      int b0c = -1; int cumc = T;
      if (cumc < 25 && cumc + h3 >= 25) b0c = 3;
      else { cumc += h3;
        if (cumc < 25 && cumc + h2 >= 25) b0c = 2;
        else { cumc += h2;
          if (cumc < 25 && cumc + h1 >= 25) b0c = 1;
          else { cumc += h1;
            if (cumc < 25 && cumc + h0 >= 25) b0c = 0;
          }
        }
      }
      u64 bal = __ballot(b0c >= 0);
      int ls = __ffsll(bal) - 1;
      int b0 = __shfl(b0c, ls);
      int cum = __shfl(cumc, ls);
      int bl = __shfl(lane, ls);
      if (lane == 0) { scr2[0] = 4*bl + b0; scr2[1] = cum; }
    }
    __syncthreads();
    prefix |= ((u32)scr2[0]) << shift;
    base_gt = scr2[1];
  }
  u32 K25 = prefix;
#pragma unroll
  for (int i = 0; i < 4; i++) {
    if (kk[i] > K25) {
      int p = atomicAdd(&cgt, 1);
      win[p] = ((u64)kk[i] << 32) | (u32)(0xFFFFFFFFu - (u32)col[i]);
    } else if (kk[i] == K25) {
      int p = atomicAdd(&ceq, 1);
      tie[p] = (u32)col[i];
    }
  }
  __syncthreads();
  int wc = cgt, tc = ceq, need = 25 - wc;
  if (tc == need) {
    if (t < need) win[wc + t] = ((u64)K25 << 32) | (u32)(0xFFFFFFFFu - tie[t]);
  } else if (w == 0) {
    for (int sel = 0; sel < need; sel++) {
      u32 m = 0xFFFFFFFFu;
      for (int i = lane; i < tc; i += 64) m = min(m, tie[i]);
      for (int off = 32; off; off >>= 1) m = min(m, (u32)__shfl_xor((int)m, off));
      for (int i = lane; i < tc; i += 64) if (tie[i] == m) tie[i] = 0xFFFFFFFFu;
      if (lane == 0) win[wc + sel] = ((u64)K25 << 32) | (u32)(0xFFFFFFFFu - m);
    }
  }
  __syncthreads();
  if (t < 32) {
    u64 v = (t < 25) ? win[t] : 0ULL;
#pragma unroll
    for (int kb = 2; kb <= 32; kb <<= 1) {
#pragma unroll
      for (int j = kb >> 1; j > 0; j >>= 1) {
        u64 o = __shfl_xor(v, j);
        bool dirAsc = ((t & kb) == 0);
        bool isLow = ((t & j) == 0);
        u64 mn = (v < o) ? v : o;
        u64 mx = (v < o) ? o : v;
        v = (dirAsc == isLow) ? mx : mn;   // descending
      }
    }
    if (t < 25) candu[(long)row*25 + t] = v;
  }
  if (t == 0) thr[row] = K25;
}

// ---------------- final merge: incumbents + filtered candidates -> lib ----------------
__global__ __launch_bounds__(256) void k_topk_fmerge(const u64* __restrict__ candu, const int* __restrict__ cnt,
                                                     const u64* __restrict__ candbuf, int* __restrict__ lib) {
  int lane = threadIdx.x & 63;
  int row = blockIdx.x*4 + (threadIdx.x >> 6);
  u64 v = (lane < 25) ? candu[(long)row*25 + lane] : 0ULL;
  int C = cnt[row]; if (C > CAP) C = CAP;
  for (int off = 0; off < C; off += 39) {
    int take = min(39, C - off);
    u64 x = (lane < 25) ? v : ((lane - 25 < take) ? candbuf[(long)row*CAP + off + (lane-25)] : 0ULL);
#pragma unroll
    for (int kb = 2; kb <= 64; kb <<= 1) {
#pragma unroll
      for (int j = kb >> 1; j > 0; j >>= 1) {
        u64 o = __shfl_xor(x, j);
        bool dirAsc = ((lane & kb) == 0);
        bool isLow = ((lane & j) == 0);
        u64 mn = (x < o) ? x : o;
        u64 mx = (x < o) ? o : x;
        x = (dirAsc == isLow) ? mx : mn;   // descending
      }
    }
    v = x;
  }
  if (lane < 25) lib[row*KNN + lane] = (int)(0xFFFFFFFFu - (u32)v);
}

// ---------------- DHG EdgeConv: per-k partials (NO atomics) ----------------
__global__ __launch_bounds__(256) void k_dhg_s(const float* __restrict__ x, const int* __restrict__ li,
                                               const float* __restrict__ Wkk, const float* __restrict__ bkk,
                                               const float* __restrict__ w1, float* __restrict__ coefp) {
  __shared__ float Wl[KNN][100];
  __shared__ float bk[KNN];
  __shared__ float w1s;
  int t = threadIdx.x;
  int k = blockIdx.y;
  for (int fl = t; fl < KNN*100; fl += 256) ((float*)Wl)[fl] = Wkk[k*2500 + fl];
  if (t < KNN) bk[t] = bkk[k*KNN + t];
  if (t == 32) w1s = w1[k];
  __syncthreads();
  int n = blockIdx.x*256 + t;
  int id = li[n*KNN + k];
  float4 r4[25];
  const float4* xr = (const float4*)(x + (long)id*100);
#pragma unroll
  for (int q=0;q<25;q++) r4[q] = xr[q];
  float sv[KNN];
  float mx = -INF;
#pragma unroll
  for (int j=0;j<KNN;j++) {
    float acc = bk[j];
#pragma unroll
    for (int q=0;q<25;q++) {
      float4 wvv = *(const float4*)&Wl[j][q*4];
      acc += r4[q].x*wvv.x; acc += r4[q].y*wvv.y; acc += r4[q].z*wvv.z; acc += r4[q].w*wvv.w;
    }
    sv[j] = acc;
    mx = fmaxf(mx, acc);
  }
  float se = 0.f;
#pragma unroll
  for (int j=0;j<KNN;j++){ sv[j] = expf(sv[j]-mx); se += sv[j]; }
  float sc = w1s / se;
#pragma unroll
  for (int j=0;j<KNN;j++) coefp[(long)(k*KNN + j)*NN + n] = sc*sv[j];
}

// ---------------- DHG reduce partials over k ----------------
__global__ __launch_bounds__(256) void k_dhg_reduce(const float* __restrict__ coefp, float* __restrict__ coef) {
  int g = blockIdx.x*256 + threadIdx.x;
  int j = g >> 13;
  int n = g & (NN-1);
  float s = 0.f;
#pragma unroll
  for (int k=0;k<KNN;k++) s += coefp[(long)(k*KNN + j)*NN + n];
  coef[(long)n*KNN + j] = s;
}

// ---------------- DHG pooled + fc + relu ----------------
__global__ __launch_bounds__(128) void k_dhg_pool(const float* __restrict__ x, const int* __restrict__ li,
                                                  const float* __restrict__ coef, const float* __restrict__ b1,
                                                  const float* __restrict__ fcW, const float* __restrict__ fcb,
                                                  float* __restrict__ out) {
  __shared__ float cf[KNN];
  __shared__ int id[KNN];
  __shared__ float pl[100];
  int n = blockIdx.x; int t = threadIdx.x;
  if (t < KNN) { cf[t] = coef[n*KNN+t]; id[t] = li[n*KNN+t]; }
  __syncthreads();
  if (t < 100) {
    float acc = b1[0];
#pragma unroll
    for (int j=0;j<KNN;j++) acc += cf[j] * x[(long)id[j]*100 + t];
    pl[t] = acc;
  }
  __syncthreads();
  if (t < 100) {
    float o = fcb[t];
    for (int d=0; d<100; d++) o += pl[d] * fcW[d*100 + t];
    out[(long)n*100 + t] = fmaxf(o, 0.f);
  }
}

// ---------------- Attention modules + softmax fusion ----------------
__global__ __launch_bounds__(128) void k_final(const float* __restrict__ f2b, const float* __restrict__ x2b,
    const float* __restrict__ w1a, const float* __restrict__ b1a, const float* __restrict__ ga, const float* __restrict__ bba,
    const float* __restrict__ w2a, const float* __restrict__ b2a,
    const float* __restrict__ w1b, const float* __restrict__ b1b, const float* __restrict__ gb, const float* __restrict__ bbb,
    const float* __restrict__ w2b, const float* __restrict__ b2b,
    float* __restrict__ outp) {
  __shared__ float f2[100], xr[100], hh[100], att[2];
  int n = blockIdx.x, t = threadIdx.x;
  if (t < 100) { f2[t] = f2b[(long)n*100+t]; xr[t] = x2b[(long)n*100+t]; }
  __syncthreads();
  if (t < 50) {
    float a = b1a[t];
    for (int d=0; d<100; d++) a += f2[d]*w1a[d*50+t];
    a = a*(ga[t]*rsqrtf(1.f+1e-5f)) + bba[t];
    hh[t] = 1.f/(1.f+expf(-a));
  } else if (t >= 64 && t < 114) {
    int jj = t-64;
    float a = b1b[jj];
    for (int d=0; d<100; d++) a += xr[d]*w1b[d*50+jj];
    a = a*(gb[jj]*rsqrtf(1.f+1e-5f)) + bbb[jj];
    hh[50+jj] = 1.f/(1.f+expf(-a));
  }
  __syncthreads();
  {
    int lane = t & 63, w = t >> 6;
    float c = 0.f;
    if (lane < 50) c = hh[w*50 + lane] * (w ? w2b[lane] : w2a[lane]);
    for (int off=32; off; off>>=1) c += __shfl_down(c, off);
    if (lane == 0) att[w] = c + (w ? b2b[0] : b2a[0]);
  }
  __syncthreads();
  if (t < 100) {
    float A1 = att[0], A2 = att[1];
    float mxv = fmaxf(A1, A2);
    float e1 = expf(A1-mxv), e2 = expf(A2-mxv);
    float inv = 1.f/(e1+e2);
    outp[(long)n*100+t] = (e1*inv)*f2[t] + (e2*inv)*xr[t];
  }
}

extern "C" void kernel_launch(void* const* d_in, const int* in_sizes, int n_in,
                              void* d_out, int out_size, void* d_ws, size_t ws_size,
                              hipStream_t stream) {
  (void)in_sizes; (void)n_in; (void)out_size; (void)ws_size;
  const float* inputx = (const float*)d_in[0];
  const int*   ei     = (const int*)d_in[1];
  const int*   fi     = (const int*)d_in[2];
  const float* g1W = (const float*)d_in[4],  *g1as = (const float*)d_in[5],  *g1ad = (const float*)d_in[6],  *g1b = (const float*)d_in[7];
  const float* g2W = (const float*)d_in[8],  *g2as = (const float*)d_in[9],  *g2ad = (const float*)d_in[10], *g2b = (const float*)d_in[11];
  const float* g3W = (const float*)d_in[12], *g3as = (const float*)d_in[13], *g3ad = (const float*)d_in[14], *g3b = (const float*)d_in[15];
  const float* g4W = (const float*)d_in[16], *g4as = (const float*)d_in[17], *g4ad = (const float*)d_in[18], *g4b = (const float*)d_in[19];
  const float* bng = (const float*)d_in[20], *bnb = (const float*)d_in[21];
  const float* bn1g = (const float*)d_in[22], *bn1b = (const float*)d_in[23];
  const float* d1Wkk = (const float*)d_in[24], *d1bkk = (const float*)d_in[25], *d1w1 = (const float*)d_in[26],
             * d1b1 = (const float*)d_in[27], *d1fcW = (const float*)d_in[28], *d1fcb = (const float*)d_in[29];
  const float* d2Wkk = (const float*)d_in[30], *d2bkk = (const float*)d_in[31], *d2w1 = (const float*)d_in[32],
             * d2b1 = (const float*)d_in[33], *d2fcW = (const float*)d_in[34], *d2fcb = (const float*)d_in[35];
  const float* a1W1 = (const float*)d_in[36], *a1b1 = (const float*)d_in[37], *a1g = (const float*)d_in[38],
             * a1bb = (const float*)d_in[39], *a1W2 = (const float*)d_in[40], *a1b2 = (const float*)d_in[41];
  const float* a2W1 = (const float*)d_in[42], *a2b1 = (const float*)d_in[43], *a2g = (const float*)d_in[44],
             * a2bb = (const float*)d_in[45], *a2W2 = (const float*)d_in[46], *a2b2 = (const float*)d_in[47];

  char* wbase = (char*)d_ws; size_t off = 0;
  auto alloc = [&](size_t b)->void*{ off = (off + 255) & ~(size_t)255; void* p = wbase + off; off += b; return p; };
  int* csrEp = (int*)alloc((NN+1)*4);
  int* csrEs = (int*)alloc((size_t)EE*4);
  int* csrFp = (int*)alloc((NN+1)*4);
  int* csrFs = (int*)alloc((size_t)EE*4);
  int* deg   = (int*)alloc(NN*4);
  int* cur   = (int*)alloc(NN*4);
  float* xp    = (float*)alloc((size_t)NN*200*4);
  float* asb   = (float*)alloc((size_t)NN*2*4);
  float* adb   = (float*)alloc((size_t)NN*2*4);
  float* feax1 = (float*)alloc((size_t)NN*100*4);
  float* x1    = (float*)alloc((size_t)NN*100*4);
  float* feax2 = (float*)alloc((size_t)NN*100*4);
  float* x2v   = (float*)alloc((size_t)NN*100*4);
  float* dtmp  = (float*)alloc((size_t)NN*100*4);
  float* xnT   = (float*)alloc((size_t)NN*100*4);      // transposed normalized features [100][8192]
  int*   lib   = (int*)alloc((size_t)NN*KNN*4);
  float* coef  = (float*)alloc((size_t)NN*KNN*4);
  u64*   candu = (u64*)alloc((size_t)NN*KNN*8);
  u32*   thr   = (u32*)alloc((size_t)NN*4);
  int*   cnt   = (int*)alloc((size_t)NN*4);
  // union scratch region (disjoint lifetimes):
  //   simbuf  [NN*INIT_COLS f32 = 32 MB]  : written k_sim, read k_topk_sel, dead after
  //   candbuf [NN*CAP u64    = 48 MB]     : written k_sim_f, read k_topk_fmerge, dead after
  //   coefp   [25*25*NN f32  = 20.5 MB]   : written k_dhg_s, read k_dhg_reduce
  size_t ubytes = (size_t)NN*CAP*8;   // 48 MB >= all three
  char* uregion = (char*)alloc(ubytes);
  float* simbuf  = (float*)uregion;
  u64*   candbuf = (u64*)uregion;
  float* coefp   = (float*)uregion;

  auto buildCSR = [&](const int* e, int* rp, int* cs){
    hipMemsetAsync(deg, 0, NN*4, stream);
    k_count<<<EE/256, 256, 0, stream>>>(e+EE, deg);
    k_scan<<<1, 1024, 0, stream>>>(deg, rp);
    hipMemsetAsync(cur, 0, NN*4, stream);
    k_scatter<<<EE/256, 256, 0, stream>>>(e, e+EE, rp, cur, cs);
  };
  buildCSR(ei, csrEp, csrEs);
  buildCSR(fi, csrFp, csrFs);

  auto GAT = [&](const float* x, int Kdim, const float* W, const float* as_w, const float* ad_w, const float* b,
                 const int* rp, const int* cs, const float* bg, const float* bb, int bnrelu, float* outb){
    k_gemm_small<<<dim3(NN/64, 4), 256, 0, stream>>>(x, W, xp, 200, Kdim);
    k_gat_coef<<<NN*4/256, 256, 0, stream>>>(xp, as_w, ad_w, asb, adb);
    k_gat_agg<<<NN, 256, 0, stream>>>(xp, asb, adb, rp, cs, b, bg, bb, bnrelu, outb);
  };
  auto DHG = [&](const float* x, const float* Wkk, const float* bkk, const float* w1p, const float* b1p,
                 const float* fcW, const float* fcb, float* outb){
    k_norm<<<NN/4, 256, 0, stream>>>(x, xnT);
    // init: cols [0, INIT_COLS) materialized; exact radix top-25 + threshold
    k_sim<<<dim3(NN/128, INIT_COLS/128), 256, 0, stream>>>(xnT, simbuf);
    k_topk_sel<<<NN, 256, 0, stream>>>(simbuf, candu, thr);
    // fused: cols [INIT_COLS, NN) filtered, never materialized (candbuf overwrites simbuf)
    hipMemsetAsync(cnt, 0, NN*4, stream);
    k_sim_f<<<dim3(NN/128, (NN-INIT_COLS)/128), 256, 0, stream>>>(xnT, thr, cnt, candbuf, INIT_COLS);
    k_topk_fmerge<<<NN/4, 256, 0, stream>>>(candu, cnt, candbuf, lib);
    k_dhg_s<<<dim3(NN/256, KNN), 256, 0, stream>>>(x, lib, Wkk, bkk, w1p, coefp);
    k_dhg_reduce<<<NN*KNN/256, 256, 0, stream>>>(coefp, coef);
    k_dhg_pool<<<NN, 128, 0, stream>>>(x, lib, coef, b1p, fcW, fcb, outb);
  };

  GAT(inputx, 200, g1W, g1as, g1ad, g1b, csrFp, csrFs, bng,  bnb,  1, feax1);
  GAT(inputx, 200, g2W, g2as, g2ad, g2b, csrEp, csrEs, bn1g, bn1b, 1, x1);
  DHG(feax1, d1Wkk, d1bkk, d1w1, d1b1, d1fcW, d1fcb, dtmp);
  GAT(dtmp, 100, g3W, g3as, g3ad, g3b, csrFp, csrFs, nullptr, nullptr, 0, feax2);
  DHG(x1, d2Wkk, d2bkk, d2w1, d2b1, d2fcW, d2fcb, dtmp);
  GAT(dtmp, 100, g4W, g4as, g4ad, g4b, csrEp, csrEs, nullptr, nullptr, 0, x2v);
  k_final<<<NN, 128, 0, stream>>>(feax2, x2v, a1W1, a1b1, a1g, a1bb, a1W2, a1b2,
                                  a2W1, a2b1, a2g, a2bb, a2W2, a2b2, (float*)d_out);
}

// Round 9
// 1276.322 us; speedup vs baseline: 1.0770x; 1.0770x over previous
//
#include <hip/hip_runtime.h>
#include <math.h>

#define NN 8192
#define EE 262144
#define KNN 25
#define INIT_COLS 1024
#define CAP 768
#define INF INFINITY

typedef unsigned int u32;
typedef unsigned long long u64;

__device__ __forceinline__ float lrelu02(float x){ return x > 0.f ? x : 0.2f*x; }
__device__ __forceinline__ u32 fkey(float f){ u32 b = __float_as_uint(f); return b ^ (u32)(((int)b >> 31) | (int)0x80000000); }

// ---------------- CSR build (by dst) ----------------
__global__ __launch_bounds__(256) void k_count(const int* __restrict__ dst, int* __restrict__ deg) {
  int e = blockIdx.x*256 + threadIdx.x;
  if (e < EE) atomicAdd(&deg[dst[e]], 1);
}

__global__ __launch_bounds__(1024) void k_scan(const int* __restrict__ deg, int* __restrict__ rowptr) {
  __shared__ int lds[1024];
  int t = threadIdx.x;
  int v[8]; int s = 0;
#pragma unroll
  for (int i=0;i<8;i++){ v[i] = deg[t*8+i]; s += v[i]; }
  lds[t] = s; __syncthreads();
  for (int off=1; off<1024; off<<=1) {
    int x = (t>=off)? lds[t-off] : 0;
    __syncthreads();
    lds[t] += x;
    __syncthreads();
  }
  int base = (t==0)? 0 : lds[t-1];
  if (t==0) rowptr[0] = 0;
  int run = base;
#pragma unroll
  for (int i=0;i<8;i++){ run += v[i]; rowptr[t*8+i+1] = run; }
}

__global__ __launch_bounds__(256) void k_scatter(const int* __restrict__ src, const int* __restrict__ dst,
                          const int* __restrict__ rowptr, int* __restrict__ cursor,
                          int* __restrict__ csr) {
  int e = blockIdx.x*256 + threadIdx.x;
  if (e < EE) {
    int d = dst[e];
    int p = rowptr[d] + atomicAdd(&cursor[d], 1);
    csr[p] = src[e];
  }
}

// ---------------- small GEMM: C[8192 x Ncols] = A[8192 x K] @ B[K x Ncols] ----------------
__global__ __launch_bounds__(256) void k_gemm_small(const float* __restrict__ A, const float* __restrict__ B,
                                                    float* __restrict__ C, int Ncols, int Kdim) {
  __shared__ float Al[50][65];
  __shared__ float Bl[50][65];
  int t = threadIdx.x;
  int tr = t >> 4, tc = t & 15;
  int r0 = blockIdx.x * 64, c0 = blockIdx.y * 64;
  float acc[4][4] = {};
  for (int kc = 0; kc < Kdim; kc += 50) {
    for (int fl = t; fl < 64*50; fl += 256) {
      int m = fl / 50, k = fl - m*50;
      Al[k][m] = A[(long)(r0+m)*Kdim + kc + k];
    }
    for (int fl = t; fl < 50*64; fl += 256) {
      int k = fl >> 6, c = fl & 63;
      int cg = c0 + c;
      Bl[k][c] = (cg < Ncols) ? B[(long)(kc+k)*Ncols + cg] : 0.f;
    }
    __syncthreads();
    for (int k = 0; k < 50; k++) {
      float a_[4], b_[4];
#pragma unroll
      for (int i=0;i<4;i++) a_[i] = Al[k][tr*4+i];
#pragma unroll
      for (int j=0;j<4;j++) b_[j] = Bl[k][tc*4+j];
#pragma unroll
      for (int i=0;i<4;i++)
#pragma unroll
        for (int j=0;j<4;j++) acc[i][j] += a_[i]*b_[j];
    }
    __syncthreads();
  }
#pragma unroll
  for (int i=0;i<4;i++){
    int r = r0 + tr*4 + i;
#pragma unroll
    for (int j=0;j<4;j++){
      int c = c0 + tc*4 + j;
      if (c < Ncols) C[(long)r*Ncols + c] = acc[i][j];
    }
  }
}

// ---------------- GAT attention coefficients ----------------
__global__ __launch_bounds__(256) void k_gat_coef(const float* __restrict__ xp, const float* __restrict__ as_w,
                                                  const float* __restrict__ ad_w, float* __restrict__ asb,
                                                  float* __restrict__ adb) {
  int g = blockIdx.x*256 + threadIdx.x;
  int n = g >> 2, q = g & 3;
  int h = q >> 1, sd = q & 1;
  const float4* xr = (const float4*)(xp + (long)n*200 + h*100);
  const float4* wr = (const float4*)((sd ? ad_w : as_w) + h*100);
  float acc = 0.f;
#pragma unroll
  for (int q4=0;q4<25;q4++){
    float4 xv = xr[q4], wv = wr[q4];
    acc += xv.x*wv.x + xv.y*wv.y + xv.z*wv.z + xv.w*wv.w;
  }
  (sd ? adb : asb)[n*2 + h] = acc;
}

// ---------------- GAT aggregation per dst node ----------------
__global__ __launch_bounds__(256) void k_gat_agg(const float* __restrict__ xp, const float* __restrict__ asb,
                                                 const float* __restrict__ adb, const int* __restrict__ rowptr,
                                                 const int* __restrict__ csr, const float* __restrict__ bias,
                                                 const float* __restrict__ bng, const float* __restrict__ bnb,
                                                 int bnrelu, float* __restrict__ out) {
  __shared__ int esrc[256];
  __shared__ float ew0[256], ew1[256];
  __shared__ float red[2][4];
  __shared__ float ohead[200];
  int i = blockIdx.x, t = threadIdx.x;
  int lane = t & 63, wv = t >> 6;
  int beg = rowptr[i];
  int deg = rowptr[i+1] - beg;
  float ad0 = adb[i*2+0], ad1 = adb[i*2+1];
  float m0 = -INF, m1 = -INF, z0 = 0.f, z1 = 0.f, acc = 0.f;
  int h = (t >= 100) ? 1 : 0;
  int tot = deg + 1;
  for (int base = 0; base < tot; base += 256) {
    int cnt = min(256, tot - base);
    int j = base + t;
    float e0 = -INF, e1 = -INF; int s = i;
    if (t < cnt) {
      if (j < deg) s = csr[beg + j];
      float as0 = asb[s*2+0], as1 = asb[s*2+1];
      e0 = lrelu02(as0 + ad0);
      e1 = lrelu02(as1 + ad1);
    }
    esrc[t] = s;
    float r0v = e0, r1v = e1;
    for (int off=32; off; off>>=1){ r0v = fmaxf(r0v, __shfl_xor(r0v,off)); r1v = fmaxf(r1v, __shfl_xor(r1v,off)); }
    if (lane == 0){ red[0][wv] = r0v; red[1][wv] = r1v; }
    __syncthreads();
    float nm0 = fmaxf(m0, fmaxf(fmaxf(red[0][0],red[0][1]), fmaxf(red[0][2],red[0][3])));
    float nm1 = fmaxf(m1, fmaxf(fmaxf(red[1][0],red[1][1]), fmaxf(red[1][2],red[1][3])));
    float w0 = (t<cnt)? expf(e0-nm0) : 0.f;
    float w1e = (t<cnt)? expf(e1-nm1) : 0.f;
    ew0[t] = w0; ew1[t] = w1e;
    float s0 = w0, s1 = w1e;
    for (int off=32; off; off>>=1){ s0 += __shfl_xor(s0,off); s1 += __shfl_xor(s1,off); }
    __syncthreads();
    if (lane == 0){ red[0][wv] = s0; red[1][wv] = s1; }
    __syncthreads();
    float cs0 = red[0][0]+red[0][1]+red[0][2]+red[0][3];
    float cs1 = red[1][0]+red[1][1]+red[1][2]+red[1][3];
    float rf0 = expf(m0 - nm0);
    float rf1 = expf(m1 - nm1);
    z0 = z0*rf0 + cs0; z1 = z1*rf1 + cs1;
    m0 = nm0; m1 = nm1;
    if (t < 200) {
      acc *= (h==0) ? rf0 : rf1;
      const float* ew = (h==0) ? ew0 : ew1;
      for (int jj = 0; jj < cnt; jj++) {
        acc += ew[jj] * xp[(long)esrc[jj]*200 + t];
      }
    }
    __syncthreads();
  }
  if (t < 200) ohead[t] = acc / ((h==0) ? z0 : z1);
  __syncthreads();
  if (t < 100) {
    float v = 0.5f*(ohead[t] + ohead[100+t]) + bias[t];
    if (bnrelu) {
      v = v * (bng[t]*rsqrtf(1.f+1e-5f)) + bnb[t];
      v = fmaxf(v, 0.f);
    }
    out[(long)i*100 + t] = v;
  }
}

// ---------------- row L2-normalize -> TRANSPOSED output xnT[100][8192] ----------------
__global__ __launch_bounds__(256) void k_norm(const float* __restrict__ x, float* __restrict__ xnT) {
  int w = threadIdx.x >> 6, lane = threadIdx.x & 63;
  long n = blockIdx.x*4 + w;
  float a = x[n*100 + lane];
  float b = (lane < 36) ? x[n*100 + 64 + lane] : 0.f;
  float ss = a*a + b*b;
  for (int off=32; off; off>>=1) ss += __shfl_xor(ss, off);
  float sc = 1.f / fmaxf(sqrtf(ss), 1e-12f);
  xnT[(long)lane*NN + n] = a*sc;
  if (lane < 36) xnT[(long)(64+lane)*NN + n] = b*sc;
}

// ---------------- sim init GEMM from xnT (materialized, cols [0, INIT_COLS)) ----------------
// K-chunk 50 (round-6 barrier structure) + conflict-free fragment map:
// rows {4tr+i, 64+4tr+i}, cols {4tc+j, 64+4tc+j} -> b128 reads 2-way (free)/broadcast.
__global__ __launch_bounds__(256) void k_sim(const float* __restrict__ xnT, float* __restrict__ simbuf) {
  __shared__ float Al[50][132];
  __shared__ float Bl[50][132];
  int t = threadIdx.x;
  int tr = t >> 4, tc = t & 15;
  int r0 = blockIdx.x * 128;
  int cb = blockIdx.y * 128;
  float acc[8][8] = {};
  for (int kc = 0; kc < 100; kc += 50) {
    for (int fl = t; fl < 50*128; fl += 256) {
      int k = fl >> 7, m = fl & 127;
      const float* src = xnT + (long)(kc+k)*NN;
      Al[k][m] = src[r0 + m];
      Bl[k][m] = src[cb + m];
    }
    __syncthreads();
    for (int k = 0; k < 50; k++) {
      float4 a0 = *(const float4*)&Al[k][4*tr];
      float4 a1 = *(const float4*)&Al[k][4*tr + 64];
      float4 b0 = *(const float4*)&Bl[k][4*tc];
      float4 b1 = *(const float4*)&Bl[k][4*tc + 64];
      float a_[8] = {a0.x,a0.y,a0.z,a0.w,a1.x,a1.y,a1.z,a1.w};
      float b_[8] = {b0.x,b0.y,b0.z,b0.w,b1.x,b1.y,b1.z,b1.w};
#pragma unroll
      for (int i=0;i<8;i++)
#pragma unroll
        for (int j=0;j<8;j++) acc[i][j] += a_[i]*b_[j];
    }
    __syncthreads();
  }
#pragma unroll
  for (int i=0;i<8;i++){
    long r = r0 + ((i<4) ? (4*tr + i) : (64 + 4*tr + i - 4));
    float* crow = simbuf + r*(long)INIT_COLS + cb;
    float4 o0 = make_float4(acc[i][0],acc[i][1],acc[i][2],acc[i][3]);
    float4 o1 = make_float4(acc[i][4],acc[i][5],acc[i][6],acc[i][7]);
    *(float4*)&crow[4*tc]      = o0;
    *(float4*)&crow[64 + 4*tc] = o1;
  }
}

// ---------------- fused sim + threshold filter (cols [INIT_COLS, NN)) ----------------
// K-chunk 50 + conflict-free fragment map; survivor compaction via 16-lane scan,
// one atomic per (row, block).
__global__ __launch_bounds__(256) void k_sim_f(const float* __restrict__ xnT, const u32* __restrict__ thr,
                                               int* __restrict__ cnt, u64* __restrict__ candbuf, int cbase) {
  __shared__ float Al[50][132];
  __shared__ float Bl[50][132];
  int t = threadIdx.x;
  int tr = t >> 4, tc = t & 15;
  int r0 = blockIdx.x * 128;
  int cb = blockIdx.y * 128;
  float acc[8][8] = {};
  for (int kc = 0; kc < 100; kc += 50) {
    for (int fl = t; fl < 50*128; fl += 256) {
      int k = fl >> 7, m = fl & 127;
      const float* src = xnT + (long)(kc+k)*NN;
      Al[k][m] = src[r0 + m];
      Bl[k][m] = src[cbase + cb + m];
    }
    __syncthreads();
    for (int k = 0; k < 50; k++) {
      float4 a0 = *(const float4*)&Al[k][4*tr];
      float4 a1 = *(const float4*)&Al[k][4*tr + 64];
      float4 b0 = *(const float4*)&Bl[k][4*tc];
      float4 b1 = *(const float4*)&Bl[k][4*tc + 64];
      float a_[8] = {a0.x,a0.y,a0.z,a0.w,a1.x,a1.y,a1.z,a1.w};
      float b_[8] = {b0.x,b0.y,b0.z,b0.w,b1.x,b1.y,b1.z,b1.w};
#pragma unroll
      for (int i=0;i<8;i++)
#pragma unroll
        for (int j=0;j<8;j++) acc[i][j] += a_[i]*b_[j];
    }
    __syncthreads();
  }
  int sub = t & 15;   // == tc; 16-lane groups share the same 8 rows (same tr)
#pragma unroll
  for (int i=0;i<8;i++){
    int r = r0 + ((i<4) ? (4*tr + i) : (64 + 4*tr + i - 4));
    u32 T = thr[r];
    unsigned m8 = 0;
#pragma unroll
    for (int j=0;j<8;j++) if (fkey(acc[i][j]) > T) m8 |= 1u<<j;
    int c_lane = __popc(m8);
    int pre = c_lane;
#pragma unroll
    for (int off=1; off<16; off<<=1){ int o = __shfl_up(pre, off, 16); if (sub >= off) pre += o; }
    int tot = __shfl(pre, 15, 16);
    if (tot > 0){
      int base = 0;
      if (sub == 15) base = atomicAdd(&cnt[r], tot);
      base = __shfl(base, 15, 16);
      int p = base + pre - c_lane;
#pragma unroll
      for (int j=0;j<8;j++) if (m8 & (1u<<j)){
        if (p < CAP){
          int c = cbase + cb + ((j<4) ? (4*tc + j) : (64 + 4*tc + j - 4));
          candbuf[(long)r*CAP + p] = ((u64)fkey(acc[i][j]) << 32) | (u32)(0xFFFFFFFFu - (u32)c);
        }
        p++;
      }
    }
  }
}

// ---------------- init top-k via exact radix select over INIT_COLS ----------------
__global__ __launch_bounds__(256) void k_topk_sel(const float* __restrict__ simbuf,
                                                  u64* __restrict__ candu, u32* __restrict__ thr) {
  __shared__ int hist[256];
  __shared__ int scr2[2];
  __shared__ int cgt, ceq;
  __shared__ u64 win[32];
  __shared__ u32 tie[INIT_COLS];
  int row = blockIdx.x, t = threadIdx.x, lane = t & 63, w = t >> 6;
  const float* srow = simbuf + (long)row*INIT_COLS;
  u32 kk[4]; int col[4];
  {
    int c0 = 4*t;
    float4 f = *(const float4*)&srow[c0];
    kk[0] = fkey(f.x); col[0] = c0;
    kk[1] = fkey(f.y); col[1] = c0+1;
    kk[2] = fkey(f.z); col[2] = c0+2;
    kk[3] = fkey(f.w); col[3] = c0+3;
  }
  u32 prefix = 0; int base_gt = 0;
#pragma unroll
  for (int lvl = 0; lvl < 4; lvl++) {
    int shift = 24 - 8*lvl;
    hist[t] = 0;
    if (lvl == 0 && t == 0) { cgt = 0; ceq = 0; }
    __syncthreads();
    u32 mhi = (lvl == 0) ? 0u : (0xFFFFFFFFu << (32 - 8*lvl));
#pragma unroll
    for (int i = 0; i < 4; i++)
      if ((kk[i] & mhi) == (prefix & mhi)) atomicAdd(&hist[(kk[i] >> shift) & 0xFF], 1);
    __syncthreads();
    if (w == 0) {
      int h0 = hist[4*lane], h1 = hist[4*lane+1], h2 = hist[4*lane+2], h3 = hist[4*lane+3];
      int s = h0 + h1 + h2 + h3;
      int acc = s;
      for (int off = 1; off < 64; off <<= 1) {
        int o = __shfl_down(acc, off);
        if (lane + off < 64) acc += o;
      }
      int T = base_gt + (acc - s);
      int b0c = -1; int cumc = T;
      if (cumc < 25 && cumc + h3 >= 25) b0c = 3;
      else { cumc += h3;
        if (cumc < 25 && cumc + h2 >= 25) b0c = 2;
        else { cumc += h2;
          if (cumc < 25 && cumc + h1 >= 25) b0c = 1;
          else { cumc += h1;
            if (cumc < 25 && cumc + h0 >= 25) b0c = 0;
          }
        }
      }
      u64 bal = __ballot(b0c >= 0);
      int ls = __ffsll(bal) - 1;
      int b0 = __shfl(b0c, ls);
      int cum = __shfl(cumc, ls);
      int bl = __shfl(lane, ls);
      if (lane == 0) { scr2[0] = 4*bl + b0; scr2[1] = cum; }
    }
    __syncthreads();
    prefix |= ((u32)scr2[0]) << shift;
    base_gt = scr2[1];
  }
  u32 K25 = prefix;
#pragma unroll
  for (int i = 0; i < 4; i++) {
    if (kk[i] > K25) {
      int p = atomicAdd(&cgt, 1);
      win[p] = ((u64)kk[i] << 32) | (u32)(0xFFFFFFFFu - (u32)col[i]);
    } else if (kk[i] == K25) {
      int p = atomicAdd(&ceq, 1);
      tie[p] = (u32)col[i];
    }
  }
  __syncthreads();
  int wc = cgt, tc = ceq, need = 25 - wc;
  if (tc == need) {
    if (t < need) win[wc + t] = ((u64)K25 << 32) | (u32)(0xFFFFFFFFu - tie[t]);
  } else if (w == 0) {
    for (int sel = 0; sel < need; sel++) {
      u32 m = 0xFFFFFFFFu;
      for (int i = lane; i < tc; i += 64) m = min(m, tie[i]);
      for (int off = 32; off; off >>= 1) m = min(m, (u32)__shfl_xor((int)m, off));
      for (int i = lane; i < tc; i += 64) if (tie[i] == m) tie[i] = 0xFFFFFFFFu;
      if (lane == 0) win[wc + sel] = ((u64)K25 << 32) | (u32)(0xFFFFFFFFu - m);
    }
  }
  __syncthreads();
  if (t < 32) {
    u64 v = (t < 25) ? win[t] : 0ULL;
#pragma unroll
    for (int kb = 2; kb <= 32; kb <<= 1) {
#pragma unroll
      for (int j = kb >> 1; j > 0; j >>= 1) {
        u64 o = __shfl_xor(v, j);
        bool dirAsc = ((t & kb) == 0);
        bool isLow = ((t & j) == 0);
        u64 mn = (v < o) ? v : o;
        u64 mx = (v < o) ? o : v;
        v = (dirAsc == isLow) ? mx : mn;   // descending
      }
    }
    if (t < 25) candu[(long)row*25 + t] = v;
  }
  if (t == 0) thr[row] = K25;
}

// ---------------- final merge: incumbents + filtered candidates -> lib ----------------
__global__ __launch_bounds__(256) void k_topk_fmerge(const u64* __restrict__ candu, const int* __restrict__ cnt,
                                                     const u64* __restrict__ candbuf, int* __restrict__ lib) {
  int lane = threadIdx.x & 63;
  int row = blockIdx.x*4 + (threadIdx.x >> 6);
  u64 v = (lane < 25) ? candu[(long)row*25 + lane] : 0ULL;
  int C = cnt[row]; if (C > CAP) C = CAP;
  for (int off = 0; off < C; off += 39) {
    int take = min(39, C - off);
    u64 x = (lane < 25) ? v : ((lane - 25 < take) ? candbuf[(long)row*CAP + off + (lane-25)] : 0ULL);
#pragma unroll
    for (int kb = 2; kb <= 64; kb <<= 1) {
#pragma unroll
      for (int j = kb >> 1; j > 0; j >>= 1) {
        u64 o = __shfl_xor(x, j);
        bool dirAsc = ((lane & kb) == 0);
        bool isLow = ((lane & j) == 0);
        u64 mn = (x < o) ? x : o;
        u64 mx = (x < o) ? o : x;
        x = (dirAsc == isLow) ? mx : mn;   // descending
      }
    }
    v = x;
  }
  if (lane < 25) lib[row*KNN + lane] = (int)(0xFFFFFFFFu - (u32)v);
}

// ---------------- DHG EdgeConv: per-k partials (NO atomics) ----------------
__global__ __launch_bounds__(256) void k_dhg_s(const float* __restrict__ x, const int* __restrict__ li,
                                               const float* __restrict__ Wkk, const float* __restrict__ bkk,
                                               const float* __restrict__ w1, float* __restrict__ coefp) {
  __shared__ float Wl[KNN][100];
  __shared__ float bk[KNN];
  __shared__ float w1s;
  int t = threadIdx.x;
  int k = blockIdx.y;
  for (int fl = t; fl < KNN*100; fl += 256) ((float*)Wl)[fl] = Wkk[k*2500 + fl];
  if (t < KNN) bk[t] = bkk[k*KNN + t];
  if (t == 32) w1s = w1[k];
  __syncthreads();
  int n = blockIdx.x*256 + t;
  int id = li[n*KNN + k];
  float4 r4[25];
  const float4* xr = (const float4*)(x + (long)id*100);
#pragma unroll
  for (int q=0;q<25;q++) r4[q] = xr[q];
  float sv[KNN];
  float mx = -INF;
#pragma unroll
  for (int j=0;j<KNN;j++) {
    float acc = bk[j];
#pragma unroll
    for (int q=0;q<25;q++) {
      float4 wvv = *(const float4*)&Wl[j][q*4];
      acc += r4[q].x*wvv.x; acc += r4[q].y*wvv.y; acc += r4[q].z*wvv.z; acc += r4[q].w*wvv.w;
    }
    sv[j] = acc;
    mx = fmaxf(mx, acc);
  }
  float se = 0.f;
#pragma unroll
  for (int j=0;j<KNN;j++){ sv[j] = expf(sv[j]-mx); se += sv[j]; }
  float sc = w1s / se;
#pragma unroll
  for (int j=0;j<KNN;j++) coefp[(long)(k*KNN + j)*NN + n] = sc*sv[j];
}

// ---------------- DHG reduce partials over k ----------------
__global__ __launch_bounds__(256) void k_dhg_reduce(const float* __restrict__ coefp, float* __restrict__ coef) {
  int g = blockIdx.x*256 + threadIdx.x;
  int j = g >> 13;
  int n = g & (NN-1);
  float s = 0.f;
#pragma unroll
  for (int k=0;k<KNN;k++) s += coefp[(long)(k*KNN + j)*NN + n];
  coef[(long)n*KNN + j] = s;
}

// ---------------- DHG pooled + fc + relu ----------------
__global__ __launch_bounds__(128) void k_dhg_pool(const float* __restrict__ x, const int* __restrict__ li,
                                                  const float* __restrict__ coef, const float* __restrict__ b1,
                                                  const float* __restrict__ fcW, const float* __restrict__ fcb,
                                                  float* __restrict__ out) {
  __shared__ float cf[KNN];
  __shared__ int id[KNN];
  __shared__ float pl[100];
  int n = blockIdx.x; int t = threadIdx.x;
  if (t < KNN) { cf[t] = coef[n*KNN+t]; id[t] = li[n*KNN+t]; }
  __syncthreads();
  if (t < 100) {
    float acc = b1[0];
#pragma unroll
    for (int j=0;j<KNN;j++) acc += cf[j] * x[(long)id[j]*100 + t];
    pl[t] = acc;
  }
  __syncthreads();
  if (t < 100) {
    float o = fcb[t];
    for (int d=0; d<100; d++) o += pl[d] * fcW[d*100 + t];
    out[(long)n*100 + t] = fmaxf(o, 0.f);
  }
}

// ---------------- Attention modules + softmax fusion ----------------
__global__ __launch_bounds__(128) void k_final(const float* __restrict__ f2b, const float* __restrict__ x2b,
    const float* __restrict__ w1a, const float* __restrict__ b1a, const float* __restrict__ ga, const float* __restrict__ bba,
    const float* __restrict__ w2a, const float* __restrict__ b2a,
    const float* __restrict__ w1b, const float* __restrict__ b1b, const float* __restrict__ gb, const float* __restrict__ bbb,
    const float* __restrict__ w2b, const float* __restrict__ b2b,
    float* __restrict__ outp) {
  __shared__ float f2[100], xr[100], hh[100], att[2];
  int n = blockIdx.x, t = threadIdx.x;
  if (t < 100) { f2[t] = f2b[(long)n*100+t]; xr[t] = x2b[(long)n*100+t]; }
  __syncthreads();
  if (t < 50) {
    float a = b1a[t];
    for (int d=0; d<100; d++) a += f2[d]*w1a[d*50+t];
    a = a*(ga[t]*rsqrtf(1.f+1e-5f)) + bba[t];
    hh[t] = 1.f/(1.f+expf(-a));
  } else if (t >= 64 && t < 114) {
    int jj = t-64;
    float a = b1b[jj];
    for (int d=0; d<100; d++) a += xr[d]*w1b[d*50+jj];
    a = a*(gb[jj]*rsqrtf(1.f+1e-5f)) + bbb[jj];
    hh[50+jj] = 1.f/(1.f+expf(-a));
  }
  __syncthreads();
  {
    int lane = t & 63, w = t >> 6;
    float c = 0.f;
    if (lane < 50) c = hh[w*50 + lane] * (w ? w2b[lane] : w2a[lane]);
    for (int off=32; off; off>>=1) c += __shfl_down(c, off);
    if (lane == 0) att[w] = c + (w ? b2b[0] : b2a[0]);
  }
  __syncthreads();
  if (t < 100) {
    float A1 = att[0], A2 = att[1];
    float mxv = fmaxf(A1, A2);
    float e1 = expf(A1-mxv), e2 = expf(A2-mxv);
    float inv = 1.f/(e1+e2);
    outp[(long)n*100+t] = (e1*inv)*f2[t] + (e2*inv)*xr[t];
  }
}

extern "C" void kernel_launch(void* const* d_in, const int* in_sizes, int n_in,
                              void* d_out, int out_size, void* d_ws, size_t ws_size,
                              hipStream_t stream) {
  (void)in_sizes; (void)n_in; (void)out_size; (void)ws_size;
  const float* inputx = (const float*)d_in[0];
  const int*   ei     = (const int*)d_in[1];
  const int*   fi     = (const int*)d_in[2];
  const float* g1W = (const float*)d_in[4],  *g1as = (const float*)d_in[5],  *g1ad = (const float*)d_in[6],  *g1b = (const float*)d_in[7];
  const float* g2W = (const float*)d_in[8],  *g2as = (const float*)d_in[9],  *g2ad = (const float*)d_in[10], *g2b = (const float*)d_in[11];
  const float* g3W = (const float*)d_in[12], *g3as = (const float*)d_in[13], *g3ad = (const float*)d_in[14], *g3b = (const float*)d_in[15];
  const float* g4W = (const float*)d_in[16], *g4as = (const float*)d_in[17], *g4ad = (const float*)d_in[18], *g4b = (const float*)d_in[19];
  const float* bng = (const float*)d_in[20], *bnb = (const float*)d_in[21];
  const float* bn1g = (const float*)d_in[22], *bn1b = (const float*)d_in[23];
  const float* d1Wkk = (const float*)d_in[24], *d1bkk = (const float*)d_in[25], *d1w1 = (const float*)d_in[26],
             * d1b1 = (const float*)d_in[27], *d1fcW = (const float*)d_in[28], *d1fcb = (const float*)d_in[29];
  const float* d2Wkk = (const float*)d_in[30], *d2bkk = (const float*)d_in[31], *d2w1 = (const float*)d_in[32],
             * d2b1 = (const float*)d_in[33], *d2fcW = (const float*)d_in[34], *d2fcb = (const float*)d_in[35];
  const float* a1W1 = (const float*)d_in[36], *a1b1 = (const float*)d_in[37], *a1g = (const float*)d_in[38],
             * a1bb = (const float*)d_in[39], *a1W2 = (const float*)d_in[40], *a1b2 = (const float*)d_in[41];
  const float* a2W1 = (const float*)d_in[42], *a2b1 = (const float*)d_in[43], *a2g = (const float*)d_in[44],
             * a2bb = (const float*)d_in[45], *a2W2 = (const float*)d_in[46], *a2b2 = (const float*)d_in[47];

  char* wbase = (char*)d_ws; size_t off = 0;
  auto alloc = [&](size_t b)->void*{ off = (off + 255) & ~(size_t)255; void* p = wbase + off; off += b; return p; };
  int* csrEp = (int*)alloc((NN+1)*4);
  int* csrEs = (int*)alloc((size_t)EE*4);
  int* csrFp = (int*)alloc((NN+1)*4);
  int* csrFs = (int*)alloc((size_t)EE*4);
  int* deg   = (int*)alloc(NN*4);
  int* cur   = (int*)alloc(NN*4);
  float* xp    = (float*)alloc((size_t)NN*200*4);
  float* asb   = (float*)alloc((size_t)NN*2*4);
  float* adb   = (float*)alloc((size_t)NN*2*4);
  float* feax1 = (float*)alloc((size_t)NN*100*4);
  float* x1    = (float*)alloc((size_t)NN*100*4);
  float* feax2 = (float*)alloc((size_t)NN*100*4);
  float* x2v   = (float*)alloc((size_t)NN*100*4);
  float* dtmp  = (float*)alloc((size_t)NN*100*4);
  float* xnT   = (float*)alloc((size_t)NN*100*4);      // transposed normalized features [100][8192]
  int*   lib   = (int*)alloc((size_t)NN*KNN*4);
  float* coef  = (float*)alloc((size_t)NN*KNN*4);
  u64*   candu = (u64*)alloc((size_t)NN*KNN*8);
  u32*   thr   = (u32*)alloc((size_t)NN*4);
  int*   cnt   = (int*)alloc((size_t)NN*4);
  // union scratch region (disjoint lifetimes):
  //   simbuf  [NN*INIT_COLS f32 = 32 MB]  : written k_sim, read k_topk_sel, dead after
  //   candbuf [NN*CAP u64    = 48 MB]     : written k_sim_f, read k_topk_fmerge, dead after
  //   coefp   [25*25*NN f32  = 20.5 MB]   : written k_dhg_s, read k_dhg_reduce
  size_t ubytes = (size_t)NN*CAP*8;   // 48 MB >= all three
  char* uregion = (char*)alloc(ubytes);
  float* simbuf  = (float*)uregion;
  u64*   candbuf = (u64*)uregion;
  float* coefp   = (float*)uregion;

  auto buildCSR = [&](const int* e, int* rp, int* cs){
    hipMemsetAsync(deg, 0, NN*4, stream);
    k_count<<<EE/256, 256, 0, stream>>>(e+EE, deg);
    k_scan<<<1, 1024, 0, stream>>>(deg, rp);
    hipMemsetAsync(cur, 0, NN*4, stream);
    k_scatter<<<EE/256, 256, 0, stream>>>(e, e+EE, rp, cur, cs);
  };
  buildCSR(ei, csrEp, csrEs);
  buildCSR(fi, csrFp, csrFs);

  auto GAT = [&](const float* x, int Kdim, const float* W, const float* as_w, const float* ad_w, const float* b,
                 const int* rp, const int* cs, const float* bg, const float* bb, int bnrelu, float* outb){
    k_gemm_small<<<dim3(NN/64, 4), 256, 0, stream>>>(x, W, xp, 200, Kdim);
    k_gat_coef<<<NN*4/256, 256, 0, stream>>>(xp, as_w, ad_w, asb, adb);
    k_gat_agg<<<NN, 256, 0, stream>>>(xp, asb, adb, rp, cs, b, bg, bb, bnrelu, outb);
  };
  auto DHG = [&](const float* x, const float* Wkk, const float* bkk, const float* w1p, const float* b1p,
                 const float* fcW, const float* fcb, float* outb){
    k_norm<<<NN/4, 256, 0, stream>>>(x, xnT);
    // init: cols [0, INIT_COLS) materialized; exact radix top-25 + threshold
    k_sim<<<dim3(NN/128, INIT_COLS/128), 256, 0, stream>>>(xnT, simbuf);
    k_topk_sel<<<NN, 256, 0, stream>>>(simbuf, candu, thr);
    // fused: cols [INIT_COLS, NN) filtered, never materialized (candbuf overwrites simbuf)
    hipMemsetAsync(cnt, 0, NN*4, stream);
    k_sim_f<<<dim3(NN/128, (NN-INIT_COLS)/128), 256, 0, stream>>>(xnT, thr, cnt, candbuf, INIT_COLS);
    k_topk_fmerge<<<NN/4, 256, 0, stream>>>(candu, cnt, candbuf, lib);
    k_dhg_s<<<dim3(NN/256, KNN), 256, 0, stream>>>(x, lib, Wkk, bkk, w1p, coefp);
    k_dhg_reduce<<<NN*KNN/256, 256, 0, stream>>>(coefp, coef);
    k_dhg_pool<<<NN, 128, 0, stream>>>(x, lib, coef, b1p, fcW, fcb, outb);
  };

  GAT(inputx, 200, g1W, g1as, g1ad, g1b, csrFp, csrFs, bng,  bnb,  1, feax1);
  GAT(inputx, 200, g2W, g2as, g2ad, g2b, csrEp, csrEs, bn1g, bn1b, 1, x1);
  DHG(feax1, d1Wkk, d1bkk, d1w1, d1b1, d1fcW, d1fcb, dtmp);
  GAT(dtmp, 100, g3W, g3as, g3ad, g3b, csrFp, csrFs, nullptr, nullptr, 0, feax2);
  DHG(x1, d2Wkk, d2bkk, d2w1, d2b1, d2fcW, d2fcb, dtmp);
  GAT(dtmp, 100, g4W, g4as, g4ad, g4b, csrEp, csrEs, nullptr, nullptr, 0, x2v);
  k_final<<<NN, 128, 0, stream>>>(feax2, x2v, a1W1, a1b1, a1g, a1bb, a1W2, a1b2,
                                  a2W1, a2b1, a2g, a2bb, a2W2, a2b2, (float*)d_out);
}